// Round 7
// baseline (118.513 us; speedup 1.0000x reference)
//
#include <hip/hip_runtime.h>
#include <math.h>

// B=16, N=128, h=256, goal_dim=64, obs_dim=128, local=64, skills=16

typedef float f32x4 __attribute__((ext_vector_type(4)));
typedef short s16x8 __attribute__((ext_vector_type(8)));

// ---- output layout (float offsets, tuple return order) ----
#define LOGIT_OFF 0        // [16][128][16]
#define MASK_OFF  32768    // [16][128][128]
#define ATTN_OFF  294912   // [16][128][128]
#define OUT_OFF   557056   // [16][128][256]

// ---- dynamic LDS layout (byte offsets) ----
#define S_ABF   0          // bf16 [128][136]  agents rows (batch)      34816
#define S_GBF   34816      // bf16 [16][72]    goal rows (q-tile)        2304
#define S_QBF   37120      // bf16 [16][264]   Q rows                    8448
#define S_KV    45568      // union: Kbf bf16[128][264] / VT bf16[256][136] 69632
#define S_SP    115200     // f32 [16][132]    logits                    8448
#define S_WB    123648     // bf16 [16][136]   attn*mask                 4352
#define S_IB    128000     // bf16 [16][264]   info                      8448
#define S_OUTB  136448     // f32 [16][260]    out rows                 16640
#define S_RED1  153088     // f32 [32]  row max partials                  128
#define S_RED2  153216     // f32 [32]  row sum partials                   128
#define SMEM_BYTES 153344

static __device__ __forceinline__ unsigned short f2bf(float x) {
  unsigned int u = __float_as_uint(x);
  u = (u + 0x7fffu + ((u >> 16) & 1u)) >> 16;   // RNE
  return (unsigned short)u;
}

static __device__ __forceinline__ unsigned int cvtpk(float a, float b) {
  unsigned int d;
  asm("v_cvt_pk_bf16_f32 %0, %1, %2" : "=v"(d) : "v"(a), "v"(b));
  return d;   // low16 = bf16(a), high16 = bf16(b)
}

// build a bf16 MFMA fragment from 8 consecutive f32 in global memory
static __device__ __forceinline__ s16x8 g2frag(const float* __restrict__ p) {
  float4 x = *(const float4*)p;
  float4 y = *(const float4*)(p + 4);
  union { unsigned int u[4]; s16x8 v; } r;
  r.u[0] = cvtpk(x.x, x.y); r.u[1] = cvtpk(x.z, x.w);
  r.u[2] = cvtpk(y.x, y.y); r.u[3] = cvtpk(y.z, y.w);
  return r.v;
}

#define MFMA(a, b, c) __builtin_amdgcn_mfma_f32_16x16x32_bf16((a), (b), (c), 0, 0, 0)

// 128 blocks x 1024 threads. block = (batch b = bid>>3, 16-row q-tile).
// Fully self-contained: in-block Q/K/V projections (weights read from global
// f32 row-major as B-fragments), logits, gumbel-softmax, PV, out-proj, skills.
__global__ __launch_bounds__(1024) void mono_k(
    const float* __restrict__ goals, const float* __restrict__ agents,
    const float* __restrict__ agents_local,
    const float* __restrict__ u1, const float* __restrict__ u2,
    const float* __restrict__ Wq, const float* __restrict__ bq,
    const float* __restrict__ Wk, const float* __restrict__ bk,
    const float* __restrict__ Wv, const float* __restrict__ bv,
    const float* __restrict__ Wo, const float* __restrict__ bo,
    const float* __restrict__ Wsm, const float* __restrict__ bs,
    float* __restrict__ out) {
  extern __shared__ char smem[];
  unsigned short* abf = (unsigned short*)(smem + S_ABF);
  unsigned short* gbf = (unsigned short*)(smem + S_GBF);
  unsigned short* Qbf = (unsigned short*)(smem + S_QBF);
  unsigned short* Kbf = (unsigned short*)(smem + S_KV);   // phase P..L
  unsigned short* VT  = (unsigned short*)(smem + S_KV);   // phase V..I (alias)
  float*          Sp  = (float*)(smem + S_SP);
  unsigned short* Wb  = (unsigned short*)(smem + S_WB);
  unsigned short* Ib  = (unsigned short*)(smem + S_IB);
  float*          outb= (float*)(smem + S_OUTB);
  float*          red1= (float*)(smem + S_RED1);
  float*          red2= (float*)(smem + S_RED2);

  float* o_logit = out + LOGIT_OFF;
  float* o_mask  = out + MASK_OFF;
  float* o_attn  = out + ATTN_OFF;
  float* o_out   = out + OUT_OFF;

  int t = threadIdx.x;
  int bid = blockIdx.x;
  int b = bid >> 3, n0 = (bid & 7) << 4;
  int row0 = b * 128 + n0;
  int w = t >> 6, l = t & 63, lr = l & 15, lc = l >> 4;

  // ---- stage agents (bf16) ----
  {
    int m = t >> 3, seg = t & 7;
    const float4* src = (const float4*)(agents + ((size_t)(b * 128 + m)) * 128 + seg * 16);
    float4 a0 = src[0], a1 = src[1], a2 = src[2], a3 = src[3];
    uint4 w0 = { cvtpk(a0.x,a0.y), cvtpk(a0.z,a0.w), cvtpk(a1.x,a1.y), cvtpk(a1.z,a1.w) };
    uint4 w1 = { cvtpk(a2.x,a2.y), cvtpk(a2.z,a2.w), cvtpk(a3.x,a3.y), cvtpk(a3.z,a3.w) };
    uint4* dst = (uint4*)(abf + m * 136 + seg * 16);
    dst[0] = w0; dst[1] = w1;
  }
  // ---- stage goals (bf16) ----
  if (t < 128) {
    int n = t >> 3, seg = t & 7;
    const float4* src = (const float4*)(goals + ((size_t)(row0 + n)) * 64 + seg * 8);
    float4 g0 = src[0], g1 = src[1];
    uint4 w0 = { cvtpk(g0.x,g0.y), cvtpk(g0.z,g0.w), cvtpk(g1.x,g1.y), cvtpk(g1.z,g1.w) };
    *(uint4*)(gbf + n * 72 + seg * 8) = w0;
  }
  // ---- prefetch u1/u2 (2 rows per thread; hidden under proj phases) ----
  int pm = t & 127, prg = t >> 7;                 // prg 0..7 -> rows 2prg, 2prg+1
  float uu1a = u1[((size_t)(row0 + 2 * prg)) * 128 + pm];
  float uu1b = u1[((size_t)(row0 + 2 * prg + 1)) * 128 + pm];
  float uu2a = u2[((size_t)(row0 + 2 * prg)) * 128 + pm];
  float uu2b = u2[((size_t)(row0 + 2 * prg + 1)) * 128 + pm];
  __syncthreads();

  // ---- phase P: Q-proj + K-proj (MFMA, weights from global f32) ----
  {
    int h0 = w * 16;                               // Q: wave w -> h-tile w
    s16x8 qa0 = *(const s16x8*)(gbf + lr * 72 + lc * 8);
    s16x8 qa1 = *(const s16x8*)(gbf + lr * 72 + 32 + lc * 8);
    const float* wqp = Wq + (size_t)(h0 + lr) * 64 + lc * 8;
    f32x4 acc = {0.f, 0.f, 0.f, 0.f};
    acc = MFMA(qa0, g2frag(wqp), acc);
    acc = MFMA(qa1, g2frag(wqp + 32), acc);
    float bqv = bq[h0 + lr];
#pragma unroll
    for (int q = 0; q < 4; q++) Qbf[(4 * lc + q) * 264 + h0 + lr] = f2bf(acc[q] + bqv);
  }
  {
    int mt = w & 7;                                // K: m-tile mt, 8 h-tiles
    s16x8 ka[4];
#pragma unroll
    for (int kk = 0; kk < 4; kk++)
      ka[kk] = *(const s16x8*)(abf + (mt * 16 + lr) * 136 + kk * 32 + lc * 8);
#pragma unroll
    for (int u = 0; u < 8; u++) {
      int h0 = ((w >> 3) * 8 + u) * 16;
      const float* wkp = Wk + (size_t)(h0 + lr) * 128 + lc * 8;
      f32x4 acc = {0.f, 0.f, 0.f, 0.f};
#pragma unroll
      for (int kk = 0; kk < 4; kk++) acc = MFMA(ka[kk], g2frag(wkp + kk * 32), acc);
      float bkv = bk[h0 + lr];
#pragma unroll
      for (int q = 0; q < 4; q++) Kbf[(mt * 16 + 4 * lc + q) * 264 + h0 + lr] = f2bf(acc[q] + bkv);
    }
  }
  __syncthreads();

  // ---- phase L: logits MFMA (waves 0..7; wave = m-tile, k=256) ----
  if (w < 8) {
    int mt = w;
    f32x4 acc = {0.f, 0.f, 0.f, 0.f};
#pragma unroll
    for (int kk = 0; kk < 8; kk++) {
      s16x8 a  = *(const s16x8*)(Qbf + lr * 264 + kk * 32 + lc * 8);
      s16x8 bb = *(const s16x8*)(Kbf + (mt * 16 + lr) * 264 + kk * 32 + lc * 8);
      acc = MFMA(a, bb, acc);
    }
#pragma unroll
    for (int q = 0; q < 4; q++) Sp[(4 * lc + q) * 132 + mt * 16 + lr] = acc[q] * 0.0625f;
  }
  __syncthreads();

  // ---- phase S: gumbel-sigmoid mask + scores + softmax (2 rows/thread) ----
  {
    int half = (t >> 6) & 1;
    int ra = 2 * prg, rb = 2 * prg + 1;
    float lga = Sp[ra * 132 + pm], lgb = Sp[rb * 132 + pm];
    float g1a = -__logf(-__logf(uu1a + 1e-20f) + 1e-20f);
    float g2a = -__logf(-__logf(uu2a + 1e-20f) + 1e-20f);
    float g1b = -__logf(-__logf(uu1b + 1e-20f) + 1e-20f);
    float g2b = -__logf(-__logf(uu2b + 1e-20f) + 1e-20f);
    float mka = 1.0f / (1.0f + __expf(-(lga + g1a - g2a)));
    float mkb = 1.0f / (1.0f + __expf(-(lgb + g1b - g2b)));
    o_mask[((size_t)(row0 + ra)) * 128 + pm] = mka;
    o_mask[((size_t)(row0 + rb)) * 128 + pm] = mkb;
    float sca = lga + __logf(mka + 1e-8f);
    float scb = lgb + __logf(mkb + 1e-8f);
    float v0 = sca, v1 = scb;
#pragma unroll
    for (int off = 32; off >= 1; off >>= 1) {
      v0 = fmaxf(v0, __shfl_xor(v0, off));
      v1 = fmaxf(v1, __shfl_xor(v1, off));
    }
    if (l == 0) { red1[ra * 2 + half] = v0; red1[rb * 2 + half] = v1; }
    __syncthreads();
    float mxa = fmaxf(red1[ra * 2], red1[ra * 2 + 1]);
    float mxb = fmaxf(red1[rb * 2], red1[rb * 2 + 1]);
    float ea = __expf(sca - mxa), eb = __expf(scb - mxb);
    float s0 = ea, s1 = eb;
#pragma unroll
    for (int off = 32; off >= 1; off >>= 1) {
      s0 += __shfl_xor(s0, off);
      s1 += __shfl_xor(s1, off);
    }
    if (l == 0) { red2[ra * 2 + half] = s0; red2[rb * 2 + half] = s1; }
    __syncthreads();
    float sa = red2[ra * 2] + red2[ra * 2 + 1];
    float sb = red2[rb * 2] + red2[rb * 2 + 1];
    float ata = ea / sa, atb = eb / sb;
    o_attn[((size_t)(row0 + ra)) * 128 + pm] = ata;
    o_attn[((size_t)(row0 + rb)) * 128 + pm] = atb;
    Wb[ra * 136 + pm] = f2bf(ata * mka);
    Wb[rb * 136 + pm] = f2bf(atb * mkb);
  }
  __syncthreads();

  // ---- phase V: V-proj (MFMA), writes VT[h][m] over dead Kbf ----
  {
    int mt = w & 7;
    s16x8 va[4];
#pragma unroll
    for (int kk = 0; kk < 4; kk++)
      va[kk] = *(const s16x8*)(abf + (mt * 16 + lr) * 136 + kk * 32 + lc * 8);
#pragma unroll
    for (int u = 0; u < 8; u++) {
      int h0 = ((w >> 3) * 8 + u) * 16;
      const float* wvp = Wv + (size_t)(h0 + lr) * 128 + lc * 8;
      f32x4 acc = {0.f, 0.f, 0.f, 0.f};
#pragma unroll
      for (int kk = 0; kk < 4; kk++) acc = MFMA(va[kk], g2frag(wvp + kk * 32), acc);
      float bvv = bv[h0 + lr];
      uint2 pk;
      pk.x = cvtpk(acc[0] + bvv, acc[1] + bvv);
      pk.y = cvtpk(acc[2] + bvv, acc[3] + bvv);
      *(uint2*)(VT + (h0 + lr) * 136 + mt * 16 + 4 * lc) = pk;
    }
  }
  __syncthreads();

  // ---- phase I: info = Wb x V (A = Wb rows, B = VT rows, k=128) ----
  {
    int h0 = w * 16;
    f32x4 acc = {0.f, 0.f, 0.f, 0.f};
#pragma unroll
    for (int kk = 0; kk < 4; kk++) {
      s16x8 a  = *(const s16x8*)(Wb + lr * 136 + kk * 32 + lc * 8);
      s16x8 bb = *(const s16x8*)(VT + (h0 + lr) * 136 + kk * 32 + lc * 8);
      acc = MFMA(a, bb, acc);
    }
#pragma unroll
    for (int q = 0; q < 4; q++) Ib[(4 * lc + q) * 264 + h0 + lr] = f2bf(acc[q]);
  }
  __syncthreads();

  // ---- phase O: out = info x Wo^T + bo (B = Wo global rows, k=256) ----
  {
    int g0 = w * 16;
    const float* wop = Wo + (size_t)(g0 + lr) * 256 + lc * 8;
    f32x4 acc = {0.f, 0.f, 0.f, 0.f};
#pragma unroll
    for (int kk = 0; kk < 8; kk++) {
      s16x8 a = *(const s16x8*)(Ib + lr * 264 + kk * 32 + lc * 8);
      acc = MFMA(a, g2frag(wop + kk * 32), acc);
    }
    float bov = bo[g0 + lr];
#pragma unroll
    for (int q = 0; q < 4; q++) {
      int r = 4 * lc + q;
      float val = acc[q] + bov;
      o_out[((size_t)(row0 + r)) * 256 + g0 + lr] = val;
      outb[r * 260 + g0 + lr] = val;
    }
  }
  __syncthreads();

  // ---- phase SK: skill logits. t = (rloc<<6)|(s<<2)|p, 4-way split-K ----
  {
    int rloc = t >> 6, s = (t >> 2) & 15, p = t & 3;
    int row = row0 + rloc;
    const float4* Ws4 = (const float4*)(Wsm + s * 384);
    const float4* lp4 = (const float4*)(agents_local + (size_t)row * 64);
    const float4* gp4 = (const float4*)(goals + (size_t)row * 64);
    float acc = 0.f;
#pragma unroll
    for (int i = 0; i < 24; i++) {
      int cc = p * 96 + i * 4;
      float4 c4;
      if (cc < 64)       c4 = lp4[cc >> 2];
      else if (cc < 128) c4 = gp4[(cc - 64) >> 2];
      else               c4 = *(const float4*)&outb[rloc * 260 + (cc - 128)];
      float4 w4 = Ws4[cc >> 2];
      acc = fmaf(w4.x, c4.x, fmaf(w4.y, c4.y, fmaf(w4.z, c4.z, fmaf(w4.w, c4.w, acc))));
    }
    acc += __shfl_xor(acc, 1);
    acc += __shfl_xor(acc, 2);
    if (p == 0) o_logit[row * 16 + s] = acc + bs[s];
  }
}

extern "C" void kernel_launch(void* const* d_in, const int* in_sizes, int n_in,
                              void* d_out, int out_size, void* d_ws, size_t ws_size,
                              hipStream_t stream) {
  const float* goals        = (const float*)d_in[0];
  const float* agents       = (const float*)d_in[1];
  const float* agents_local = (const float*)d_in[2];
  const float* u1           = (const float*)d_in[3];
  const float* u2           = (const float*)d_in[4];
  const float* Wq = (const float*)d_in[5];
  const float* bq = (const float*)d_in[6];
  const float* Wk = (const float*)d_in[7];
  const float* bk = (const float*)d_in[8];
  const float* Wv = (const float*)d_in[9];
  const float* bv = (const float*)d_in[10];
  const float* Wo = (const float*)d_in[11];
  const float* bo = (const float*)d_in[12];
  const float* Wsm = (const float*)d_in[13];
  const float* bs  = (const float*)d_in[14];
  float* out = (float*)d_out;

  static int attr_done = 0;   // idempotent, deterministic (same value every call)
  if (!attr_done) {
    hipFuncSetAttribute((const void*)mono_k,
                        hipFuncAttributeMaxDynamicSharedMemorySize, SMEM_BYTES);
    attr_done = 1;
  }
  mono_k<<<128, 1024, SMEM_BYTES, stream>>>(goals, agents, agents_local, u1, u2,
                                            Wq, bq, Wk, bk, Wv, bv, Wo, bo,
                                            Wsm, bs, out);
}